// Round 9
// baseline (145.422 us; speedup 1.0000x reference)
//
#include <hip/hip_runtime.h>
#include <hip/hip_bf16.h>
#include <float.h>

// AFM via MFMA, round 9: de-serialized tiles (round-6 idea) with the correct
// register budget (round-6 failed ONLY because launch_bounds(256,6) capped at
// ~102 regs and spilled; here launch_bounds(256,4) gives 128). RPW=1: one wave
// = one row, 4096 blocks; single LDS buffer, no double-buffer/prefetch code.
// Per 32-pair tile: one v_mfma_f32_32x32x16_bf16 computes h^T = W^T@inner^T
// with bias riding in as the C operand (no C-init movs); per-pair cross
// scalar g_p = inner_p . fc_w folded into the same pass (packed-f32 math).
// Scores kept PARTIAL in sc[9] (no per-tile shfl/expf chain) -> 9 tiles are
// fully independent, ILP covers LDS/MFMA latency; epilogue batches the 9
// half-combines + max + 9 independent expf once per row.
// bf16 by truncation via v_perm (error ~1e-5 vs 2.2e-2 threshold).

#define FN 24
#define ED 16
#define AS 32
#define NP 276
#define NT 9            // 32-pair tiles (288 slots)
#define LASTV 20        // valid cols in last tile
#define EPITCH 20       // emb LDS row pitch in words (80 B, b128-aligned)
#define NTHR 256
#define FIELD_SIZE 50000

typedef __attribute__((ext_vector_type(8)))  short bf16x8;
typedef __attribute__((ext_vector_type(16))) float f32x16;
typedef __attribute__((ext_vector_type(2)))  float f32x2;

union BFR { int i[4]; bf16x8 v; };
union F4P { float4 f4; f32x2 p[2]; };

__device__ __forceinline__ short f2bf(float x) {
    union { __hip_bfloat16 h; short s; } u;
    u.h = __float2bfloat16(x);
    return u.s;
}

__global__ __launch_bounds__(NTHR, 4) void afm_kernel(
    const int*   __restrict__ x,
    const float* __restrict__ embed_table,
    const float* __restrict__ linear_table,
    const float* __restrict__ linear_bias,
    const float* __restrict__ attn_W,       // [E, A]
    const float* __restrict__ attn_b,       // [A]
    const float* __restrict__ proj_w,       // [A]
    const float* __restrict__ fc_w,         // [E]
    const float* __restrict__ fc_b,
    float*       __restrict__ out,
    int B)
{
    __shared__ float emb_s[NTHR / 64][FN * EPITCH];
    __shared__ int   pko_s[NT * 32];

    const int tid  = threadIdx.x;
    const int wave = tid >> 6;
    const int lane = tid & 63;
    const int half = lane >> 5;
    const int col  = lane & 31;
    const int e0   = half * 8;
    const int row  = blockIdx.x * (NTHR / 64) + wave;
    const int rowc = (row < B) ? row : (B - 1);

    // ---- pair table, block-cooperative ----
    for (int s = tid; s < NT * 32; s += NTHR) {
        const int p = (s < NP) ? s : (NP - 1);
        const int q = (NP - 1) - p;
        int m = (int)((sqrtf((float)(8 * q + 1)) + 1.0f) * 0.5f);
        if (m * (m + 1) / 2 <= q) ++m;
        if ((m - 1) * m / 2 > q) --m;
        const int fi = (FN - 1) - m;
        const int fj = fi + 1 + (p - (NP - m * (m + 1) / 2));
        pko_s[s] = ((fi * (EPITCH * 4)) << 16) | (fj * (EPITCH * 4));
    }

    // ---- x load + linear term ----
    const int idxv = (lane < FN) ? (x[rowc * FN + lane] + lane * FIELD_SIZE) : 0;
    const float linv = (lane < FN) ? linear_table[idxv] : 0.f;

    // ---- embedding gather -> LDS (96 float4 over 64 lanes) ----
    {
        float* emb = emb_s[wave];
        const int f0 = lane >> 2, q0 = lane & 3;
        const int id0 = __shfl(idxv, f0, 64);
        const int id1 = __shfl(idxv, 16 + f0, 64);   // meaningful for lane<32
        const float4 a = ((const float4*)(embed_table + (size_t)id0 * ED))[q0];
        *(float4*)&emb[f0 * EPITCH + q0 * 4] = a;
        if (lane < 32) {
            const float4 b = ((const float4*)(embed_table + (size_t)id1 * ED))[q0];
            *(float4*)&emb[(16 + f0) * EPITCH + q0 * 4] = b;
        }
    }

    // ---- per-lane weight constants (scalar-pipe, wave-uniform addrs) ----
    bf16x8 aW;                          // A-frag: W^T[a=col][k=e0+i]
#pragma unroll
    for (int i = 0; i < 8; ++i) aW[i] = f2bf(attn_W[(e0 + i) * AS + col]);
    f32x16 biasC;                       // D rows: a=(r&3)+8*(r>>2)+4*half
    f32x2  pw2[8];
#pragma unroll
    for (int r = 0; r < 16; ++r) {
        const int a = (r & 3) + 8 * (r >> 2) + 4 * half;
        biasC[r] = attn_b[a];
    }
#pragma unroll
    for (int r2 = 0; r2 < 8; ++r2) {
        const int a0 = (2 * r2 & 3) + 8 * (2 * r2 >> 2) + 4 * half;
        pw2[r2].x = proj_w[a0];
        pw2[r2].y = proj_w[a0 + 1];
    }
    f32x2 fcw2[4];
#pragma unroll
    for (int i = 0; i < 4; ++i) {
        fcw2[i].x = fc_w[e0 + 2 * i];
        fcw2[i].y = fc_w[e0 + 2 * i + 1];
    }
    const float cbias = linear_bias[0] + fc_b[0];

    __syncthreads();                    // pko_s ready

    // ---- 9 independent tiles: partial scores + cross scalars ----
    const char* embb = (const char*)emb_s[wave] + half * 32;
    float sc[NT], g[NT];
#pragma unroll
    for (int t = 0; t < NT; ++t) {
        const int pkv = pko_s[t * 32 + col];
        const int oi = pkv >> 16;
        const int oj = pkv & 0xffff;
        F4P xi0, xi1, xj0, xj1;
        xi0.f4 = *(const float4*)(embb + oi);
        xi1.f4 = *(const float4*)(embb + oi + 16);
        xj0.f4 = *(const float4*)(embb + oj);
        xj1.f4 = *(const float4*)(embb + oj + 16);
        const f32x2 P0 = xi0.p[0] * xj0.p[0];
        const f32x2 P1 = xi0.p[1] * xj0.p[1];
        const f32x2 P2 = xi1.p[0] * xj1.p[0];
        const f32x2 P3 = xi1.p[1] * xj1.p[1];
        f32x2 G = P0 * fcw2[0];
        G = __builtin_elementwise_fma(P1, fcw2[1], G);
        G = __builtin_elementwise_fma(P2, fcw2[2], G);
        G = __builtin_elementwise_fma(P3, fcw2[3], G);
        g[t] = G.x + G.y;
        BFR u;
        u.i[0] = __builtin_amdgcn_perm(__float_as_int(P0.y), __float_as_int(P0.x), 0x07060302);
        u.i[1] = __builtin_amdgcn_perm(__float_as_int(P1.y), __float_as_int(P1.x), 0x07060302);
        u.i[2] = __builtin_amdgcn_perm(__float_as_int(P2.y), __float_as_int(P2.x), 0x07060302);
        u.i[3] = __builtin_amdgcn_perm(__float_as_int(P3.y), __float_as_int(P3.x), 0x07060302);
        const f32x16 c = __builtin_amdgcn_mfma_f32_32x32x16_bf16(aW, u.v, biasC, 0, 0, 0);
        f32x2 sac; sac.x = 0.f; sac.y = 0.f;
        f32x2 z2;  z2.x = 0.f;  z2.y = 0.f;
#pragma unroll
        for (int r2 = 0; r2 < 8; ++r2) {
            f32x2 h; h.x = c[2 * r2]; h.y = c[2 * r2 + 1];
            h = __builtin_elementwise_max(h, z2);
            sac = __builtin_elementwise_fma(h, pw2[r2], sac);
        }
        sc[t] = sac.x + sac.y;          // PARTIAL (own a-half)
    }

    // ---- epilogue: batched half-combines, softmax, reductions ----
#pragma unroll
    for (int t = 0; t < NT; ++t) sc[t] += __shfl_xor(sc[t], 32, 64);
    float M = sc[0];
#pragma unroll
    for (int t = 1; t < NT; ++t) M = fmaxf(M, sc[t]);
    // invalid last-tile cols hold the (clamped) pair-275 score: harmless for max
#pragma unroll
    for (int off = 16; off; off >>= 1) M = fmaxf(M, __shfl_xor(M, off, 64));
    float ssum = 0.f, cp = 0.f;
#pragma unroll
    for (int t = 0; t < NT; ++t) {
        float e = __expf(sc[t] - M);
        if (t == NT - 1) e = (col < LASTV) ? e : 0.f;
        ssum += e;
        cp = fmaf(e, g[t], cp);
    }
#pragma unroll
    for (int off = 16; off; off >>= 1) ssum += __shfl_xor(ssum, off, 64);
#pragma unroll
    for (int off = 32; off; off >>= 1) cp += __shfl_xor(cp, off, 64);
    float lin = linv;
#pragma unroll
    for (int off = 32; off; off >>= 1) lin += __shfl_xor(lin, off, 64);

    if (row < B && lane == 0)
        out[row] = lin + cbias + cp / ssum;
}

extern "C" void kernel_launch(void* const* d_in, const int* in_sizes, int n_in,
                              void* d_out, int out_size, void* d_ws, size_t ws_size,
                              hipStream_t stream) {
    const int*   x            = (const int*)  d_in[0];
    const float* embed_table  = (const float*)d_in[1];
    const float* linear_table = (const float*)d_in[2];
    const float* linear_bias  = (const float*)d_in[3];
    const float* attn_W       = (const float*)d_in[4];
    const float* attn_b       = (const float*)d_in[5];
    const float* proj_w       = (const float*)d_in[6];
    // d_in[7] = proj_b (softmax-invariant)
    const float* fc_w         = (const float*)d_in[8];
    const float* fc_b         = (const float*)d_in[9];
    float* out = (float*)d_out;

    const int B = in_sizes[0] / FN;
    const int rows_per_block = NTHR / 64;           // 4
    const int grid = (B + rows_per_block - 1) / rows_per_block;
    afm_kernel<<<grid, NTHR, 0, stream>>>(x, embed_table, linear_table,
                                          linear_bias, attn_W, attn_b, proj_w,
                                          fc_w, fc_b, out, B);
}